// Round 11
// baseline (887.556 us; speedup 1.0000x reference)
//
#include <hip/hip_runtime.h>
#include <hip/hip_bf16.h>
#include <hip/hip_cooperative_groups.h>

namespace cg = cooperative_groups;

#define N_NODES 100000
#define N_EDGES 1600000
#define D 128
#define NRANGE 8
#define RANGE_SZ 12500          // nodes per level-1 range
#define SB_PER_RANGE 196        // 64-node buckets per range
#define NBUCKET (NRANGE * SB_PER_RANGE)  // 1568
#define NB_COOP 512
#define CH_PART 3125            // 512*3125 = 1,600,000 exact
#define G_DEG 128
#define CH_DEG 784              // 128*784 >= N_NODES
#define G_X2B 12500             // x2b chunks
#define PLANE ((size_t)N_NODES * 64)   // ushorts per feature-plane

typedef __attribute__((ext_vector_type(8))) short bf16x8;
typedef __attribute__((ext_vector_type(8))) unsigned short u16x8;
typedef __attribute__((ext_vector_type(4))) float f32x4;
typedef unsigned int u32;

__device__ inline ushort f2b(float x) {
    union { float f; unsigned u; } v; v.f = x;
    unsigned r = (v.u + 0x7fff + ((v.u >> 16) & 1)) >> 16;
    return (ushort)r;
}
__device__ inline float b2f(ushort b) {
    union { unsigned u; float f; } v; v.u = ((unsigned)b) << 16;
    return v.f;
}

// ---------------- one cooperative kernel: x2b ∥ hist1 ∥ wsplit → scan1 → place1
// → hist2 → scan2 → place2 → sort3 → deghist → degscan → degplace ----------------
__global__ void build_kernel(const float* __restrict__ x, ushort* __restrict__ xb,
                             const int* __restrict__ src, const int* __restrict__ dst,
                             const float* __restrict__ W1, const float* __restrict__ W2,
                             const float* __restrict__ W3,
                             ushort* __restrict__ wt_hi, ushort* __restrict__ wt_lo,
                             int* __restrict__ bhist1, int* __restrict__ cbase1,
                             int* __restrict__ rs,
                             int* __restrict__ bhist2, int* __restrict__ cbase2,
                             int* __restrict__ bucket_start,
                             u32* __restrict__ epack1, u32* __restrict__ epack2,
                             int* __restrict__ row_ptr, int* __restrict__ col,
                             int* __restrict__ deg,
                             int* __restrict__ bdh, int* __restrict__ cbdeg,
                             int* __restrict__ perm) {
    cg::grid_group grid = cg::this_grid();
    __shared__ int sh[512];
    int tid = threadIdx.x;
    int bid = blockIdx.x;

    // ---- phase 0: hist1 (my chunk) + x2b (strided chunks) + wsplit ----
    {
        if (tid < NRANGE) sh[tid] = 0;
        __syncthreads();
        int s0 = bid * CH_PART, s1 = s0 + CH_PART;
        if (s1 > N_EDGES) s1 = N_EDGES;
        for (int i = s0 + tid; i < s1; i += 256)
            atomicAdd(&sh[dst[i] / RANGE_SZ], 1);
        __syncthreads();
        if (tid < NRANGE) bhist1[bid * NRANGE + tid] = sh[tid];

        for (int c = bid; c < G_X2B; c += NB_COOP) {
            int i = c * 256 + tid;   // 12500*256 == N_NODES*D/4 exactly
            float4 v = ((const float4*)x)[i];
            ushort4 o;
            o.x = f2b(v.x); o.y = f2b(v.y); o.z = f2b(v.z); o.w = f2b(v.w);
            int node = i >> 5;
            int f0 = (i & 31) * 4;
            int plane = f0 >> 6;
            *(ushort4*)(xb + plane * PLANE + (size_t)node * 64 + (f0 & 63)) = o;
        }
        if (bid < 192) {
            int layer = bid >> 6;
            int t = (bid & 63) * 256 + tid;
            const float* W = layer == 0 ? W1 : layer == 1 ? W2 : W3;
            int k = t >> 7, n = t & 127;
            float w = W[t];
            ushort hi = f2b(w);
            ushort lo = f2b(w - b2f(hi));
            wt_hi[layer * D * D + n * D + k] = hi;
            wt_lo[layer * D * D + n * D + k] = lo;
        }
    }
    grid.sync();

    // ---- scan1 (block 0): 4 waves x 2 ranges; sh[0..7]=rtot, sh[8..15]=roff ----
    if (bid == 0) {
        int w = tid >> 6, lane = tid & 63;
        int excl[2][8];
        #pragma unroll
        for (int rr = 0; rr < 2; ++rr) {
            int r = w * 2 + rr;
            int run = 0;
            #pragma unroll
            for (int seg = 0; seg < 8; ++seg) {
                int b = seg * 64 + lane;
                int v = bhist1[b * NRANGE + r];
                int sc = v;
                #pragma unroll
                for (int off = 1; off < 64; off <<= 1) {
                    int y = __shfl_up(sc, off);
                    if (lane >= off) sc += y;
                }
                excl[rr][seg] = run + sc - v;
                run += __shfl(sc, 63);
            }
            if (lane == 63) sh[r] = run;
        }
        __syncthreads();
        if (tid == 0) {
            int a = 0;
            for (int i = 0; i < NRANGE; ++i) { sh[8 + i] = a; a += sh[i]; }
        }
        __syncthreads();
        #pragma unroll
        for (int rr = 0; rr < 2; ++rr) {
            int r = w * 2 + rr;
            int base = sh[8 + r];
            #pragma unroll
            for (int seg = 0; seg < 8; ++seg)
                cbase1[(seg * 64 + lane) * NRANGE + r] = base + excl[rr][seg];
        }
        if (tid < NRANGE) rs[tid] = sh[8 + tid];
        if (tid == 0) rs[NRANGE] = N_EDGES;
    }
    grid.sync();

    // ---- place1 (all blocks) ----
    {
        if (tid < NRANGE) sh[tid] = cbase1[bid * NRANGE + tid];
        __syncthreads();
        int s0 = bid * CH_PART, s1 = s0 + CH_PART;
        if (s1 > N_EDGES) s1 = N_EDGES;
        for (int i = s0 + tid; i < s1; i += 256) {
            int d = dst[i], s = src[i];
            int r = d / RANGE_SZ;
            int dl = d - r * RANGE_SZ;
            int p = atomicAdd(&sh[r], 1);
            epack1[p] = ((u32)dl << 17) | (u32)s;
        }
    }
    grid.sync();

    // ---- hist2 (all blocks) ----
    {
        for (int i = tid; i < SB_PER_RANGE; i += 256) sh[i] = 0;
        __syncthreads();
        int r = bid >> 6, j = bid & 63;
        int e0 = rs[r], e1 = rs[r + 1];
        int cs = (e1 - e0 + 63) >> 6;
        int s0 = e0 + j * cs, s1 = s0 + cs;
        if (s1 > e1) s1 = e1;
        for (int i = s0 + tid; i < s1; i += 256)
            atomicAdd(&sh[epack1[i] >> 23], 1);
        __syncthreads();
        for (int i = tid; i < SB_PER_RANGE; i += 256)
            bhist2[bid * SB_PER_RANGE + i] = sh[i];
    }
    grid.sync();

    // ---- scan2 (blocks 0..7): sh[0..195]=tot, sh[196..391]=base ----
    if (bid < NRANGE) {
        int r = bid;
        int sb = tid;
        if (sb < SB_PER_RANGE) {
            int s = 0;
            for (int j = 0; j < 64; ++j) s += bhist2[(r * 64 + j) * SB_PER_RANGE + sb];
            sh[sb] = s;
        }
        __syncthreads();
        if (tid == 0) {
            int a = 0;
            for (int i = 0; i < SB_PER_RANGE; ++i) { sh[196 + i] = a; a += sh[i]; }
        }
        __syncthreads();
        if (sb < SB_PER_RANGE) {
            int run = rs[r] + sh[196 + sb];
            bucket_start[r * SB_PER_RANGE + sb] = run;
            for (int j = 0; j < 64; ++j) {
                cbase2[(r * 64 + j) * SB_PER_RANGE + sb] = run;
                run += bhist2[(r * 64 + j) * SB_PER_RANGE + sb];
            }
        }
        if (r == NRANGE - 1 && tid == 0) bucket_start[NBUCKET] = N_EDGES;
    }
    grid.sync();

    // ---- place2 (all blocks) ----
    {
        for (int i = tid; i < SB_PER_RANGE; i += 256)
            sh[i] = cbase2[bid * SB_PER_RANGE + i];
        __syncthreads();
        int r = bid >> 6, j = bid & 63;
        int e0 = rs[r], e1 = rs[r + 1];
        int cs = (e1 - e0 + 63) >> 6;
        int s0 = e0 + j * cs, s1 = s0 + cs;
        if (s1 > e1) s1 = e1;
        for (int i = s0 + tid; i < s1; i += 256) {
            u32 e = epack1[i];
            int sb = e >> 23;
            int p = atomicAdd(&sh[sb], 1);
            epack2[p] = e & 0x7FFFFFu;
        }
    }
    grid.sync();

    // ---- sort3 (buckets looped over blocks): sh[0..63]=hist, sh[64..127]=cur ----
    for (int b = bid; b < NBUCKET; b += NB_COOP) {
        int r = b / SB_PER_RANGE, sb = b - r * SB_PER_RANGE;
        int node_base = r * RANGE_SZ + sb * 64;
        int nb = r * RANGE_SZ + RANGE_SZ - node_base;
        if (nb > 64) nb = 64;
        int e0 = bucket_start[b], e1 = bucket_start[b + 1];
        if (tid < 64) sh[tid] = 0;
        __syncthreads();
        for (int i = e0 + tid; i < e1; i += 256)
            atomicAdd(&sh[(epack2[i] >> 17) & 63], 1);
        __syncthreads();
        if (tid < 64) {   // wave 0
            int v = sh[tid];
            int sc = v;
            #pragma unroll
            for (int off = 1; off < 64; off <<= 1) {
                int y = __shfl_up(sc, off);
                if (tid >= off) sc += y;
            }
            int ex = e0 + sc - v;
            sh[64 + tid] = ex;
            if (tid < nb) {
                row_ptr[node_base + tid] = ex;
                deg[node_base + tid] = v;
            }
        }
        __syncthreads();
        for (int i = e0 + tid; i < e1; i += 256) {
            u32 e = epack2[i];
            int l = (e >> 17) & 63;
            int p = atomicAdd(&sh[64 + l], 1);
            col[p] = (int)(e & 0x1FFFFu);
        }
        if (b == NBUCKET - 1 && tid == 0) row_ptr[N_NODES] = N_EDGES;
        __syncthreads();  // protect sh before next iteration's zeroing
    }
    grid.sync();

    // ---- deghist (blocks 0..127) ----
    if (bid < G_DEG) {
        if (tid < 128) sh[tid] = 0;
        __syncthreads();
        int s0 = bid * CH_DEG, s1 = s0 + CH_DEG;
        if (s1 > N_NODES) s1 = N_NODES;
        for (int i = s0 + tid; i < s1; i += 256)
            atomicAdd(&sh[min(deg[i], 127)], 1);
        __syncthreads();
        if (tid < 128) bdh[bid * 128 + tid] = sh[tid];
    }
    grid.sync();

    // ---- degscan (block 0) ----
    if (bid == 0) {
        if (tid < 128) {
            int tot = 0;
            for (int j = 0; j < G_DEG; ++j) tot += bdh[j * 128 + tid];
            sh[tid] = tot;
        }
        __syncthreads();
        if (tid == 0) {
            int run = 0;
            for (int b = 127; b >= 0; --b) { int c = sh[b]; sh[b] = run; run += c; }
        }
        __syncthreads();
        if (tid < 128) {
            int run = sh[tid];
            for (int j = 0; j < G_DEG; ++j) {
                cbdeg[j * 128 + tid] = run;
                run += bdh[j * 128 + tid];
            }
        }
    }
    grid.sync();

    // ---- degplace (blocks 0..127) ----
    if (bid < G_DEG) {
        if (tid < 128) sh[tid] = cbdeg[bid * 128 + tid];
        __syncthreads();
        int s0 = bid * CH_DEG, s1 = s0 + CH_DEG;
        if (s1 > N_NODES) s1 = N_NODES;
        for (int i = s0 + tid; i < s1; i += 256) {
            int p = atomicAdd(&sh[min(deg[i], 127)], 1);
            perm[p] = i;
        }
    }
}

// ---------------- GIN layer ----------------

// plane-split aggregate: plane = blockIdx&1; 8-lane group per (node, plane).
__global__ void aggregate_kernel(const ushort* __restrict__ xb, const int* __restrict__ row_ptr,
                                 const int* __restrict__ col, const int* __restrict__ perm,
                                 const float* __restrict__ eps_p, ushort* __restrict__ hb) {
    int plane = blockIdx.x & 1;
    int task = threadIdx.x >> 3;
    int l8 = threadIdx.x & 7;
    int qidx = (blockIdx.x >> 1) * 32 + task;
    if (qidx >= N_NODES) return;
    int node = perm[qidx];
    const ushort* xp = xb + plane * PLANE;
    int beg = row_ptr[node], end = row_ptr[node + 1];
    float a0[8] = {0,0,0,0,0,0,0,0};
    float a1[8] = {0,0,0,0,0,0,0,0};
    int e = beg;
    for (; e + 7 < end; e += 8) {
        int s[8];
        #pragma unroll
        for (int j = 0; j < 8; ++j) s[j] = col[e + j];
        u16x8 v[8];
        #pragma unroll
        for (int j = 0; j < 8; ++j)
            v[j] = *(const u16x8*)(xp + ((size_t)s[j] << 6) + l8 * 8);
        #pragma unroll
        for (int j = 0; j < 8; ++j) {
            float* a = (j & 1) ? a1 : a0;
            #pragma unroll
            for (int k = 0; k < 8; ++k) a[k] += b2f(v[j][k]);
        }
    }
    if (e + 3 < end) {
        int s[4];
        #pragma unroll
        for (int j = 0; j < 4; ++j) s[j] = col[e + j];
        u16x8 v[4];
        #pragma unroll
        for (int j = 0; j < 4; ++j)
            v[j] = *(const u16x8*)(xp + ((size_t)s[j] << 6) + l8 * 8);
        #pragma unroll
        for (int j = 0; j < 4; ++j) {
            float* a = (j & 1) ? a1 : a0;
            #pragma unroll
            for (int k = 0; k < 8; ++k) a[k] += b2f(v[j][k]);
        }
        e += 4;
    }
    for (; e < end; ++e) {
        int s = col[e];
        u16x8 v = *(const u16x8*)(xp + ((size_t)s << 6) + l8 * 8);
        #pragma unroll
        for (int k = 0; k < 8; ++k) a0[k] += b2f(v[k]);
    }
    float scale = 1.0f + *eps_p;
    u16x8 xi = *(const u16x8*)(xp + ((size_t)node << 6) + l8 * 8);
    u16x8 ho;
    #pragma unroll
    for (int k = 0; k < 8; ++k) {
        float o = a0[k] + a1[k] + scale * b2f(xi[k]);
        ho[k] = f2b(o);
    }
    *(u16x8*)(hb + plane * PLANE + ((size_t)node << 6) + l8 * 8) = ho;
}

// out = relu(h @ W + b); A = bf16 h (plane layout), W = hi/lo split.
// MODE 0: write bf16 (plane layout); MODE 1: fused log_softmax, write f32 row-major.
template <int MODE>
__launch_bounds__(256, 2)
__global__ void gemm_relu_mfma(const ushort* __restrict__ hb,
                               const ushort* __restrict__ wt_hi, const ushort* __restrict__ wt_lo,
                               const float* __restrict__ bias,
                               float* __restrict__ outf, ushort* __restrict__ outb) {
    int wv = threadIdx.x >> 6, lane = threadIdx.x & 63;
    int r0 = blockIdx.x * 128 + wv * 32;
    int arow = lane & 15, agrp = lane >> 4;
    bf16x8 Ah[2][4];
    #pragma unroll
    for (int mf = 0; mf < 2; ++mf) {
        int row = r0 + mf * 16 + arow;
        size_t rb0 = (size_t)row << 6;
        #pragma unroll
        for (int kf = 0; kf < 4; ++kf) {
            size_t off = (kf < 2) ? rb0 + kf * 32 + agrp * 8
                                  : PLANE + rb0 + (kf - 2) * 32 + agrp * 8;
            Ah[mf][kf] = *(const bf16x8*)(hb + off);
        }
    }
    f32x4 acc[2][8];
    #pragma unroll
    for (int mf = 0; mf < 2; ++mf)
        #pragma unroll
        for (int nf = 0; nf < 8; ++nf)
            acc[mf][nf] = (f32x4){0.f, 0.f, 0.f, 0.f};
    #pragma unroll
    for (int nf = 0; nf < 8; ++nf) {
        #pragma unroll
        for (int kf = 0; kf < 4; ++kf) {
            size_t wb = (size_t)(nf * 16 + arow) * D + kf * 32 + agrp * 8;
            bf16x8 bh = *(const bf16x8*)(wt_hi + wb);
            bf16x8 bl = *(const bf16x8*)(wt_lo + wb);
            #pragma unroll
            for (int mf = 0; mf < 2; ++mf) {
                acc[mf][nf] = __builtin_amdgcn_mfma_f32_16x16x32_bf16(Ah[mf][kf], bh, acc[mf][nf], 0, 0, 0);
                acc[mf][nf] = __builtin_amdgcn_mfma_f32_16x16x32_bf16(Ah[mf][kf], bl, acc[mf][nf], 0, 0, 0);
            }
        }
    }
    float bcol[8];
    #pragma unroll
    for (int nf = 0; nf < 8; ++nf) bcol[nf] = bias[nf * 16 + arow];
    if (MODE == 0) {
        int crow = agrp * 4;
        #pragma unroll
        for (int mf = 0; mf < 2; ++mf) {
            #pragma unroll
            for (int nf = 0; nf < 8; ++nf) {
                int coln = nf * 16 + arow;
                size_t pbase = (nf >> 2) ? PLANE : 0;
                #pragma unroll
                for (int r = 0; r < 4; ++r) {
                    int row = r0 + mf * 16 + crow + r;
                    if (row < N_NODES)
                        outb[pbase + ((size_t)row << 6) + (coln & 63)] =
                            f2b(fmaxf(acc[mf][nf][r] + bcol[nf], 0.f));
                }
            }
        }
    } else {
        #pragma unroll
        for (int mf = 0; mf < 2; ++mf) {
            #pragma unroll
            for (int rr = 0; rr < 4; ++rr) {
                float v[8];
                #pragma unroll
                for (int nf = 0; nf < 8; ++nf)
                    v[nf] = fmaxf(acc[mf][nf][rr] + bcol[nf], 0.f);
                float m = v[0];
                #pragma unroll
                for (int nf = 1; nf < 8; ++nf) m = fmaxf(m, v[nf]);
                #pragma unroll
                for (int off = 1; off < 16; off <<= 1) m = fmaxf(m, __shfl_xor(m, off));
                float s = 0.f;
                #pragma unroll
                for (int nf = 0; nf < 8; ++nf) s += __expf(v[nf] - m);
                #pragma unroll
                for (int off = 1; off < 16; off <<= 1) s += __shfl_xor(s, off);
                float lse = m + __logf(s);
                int row = r0 + mf * 16 + agrp * 4 + rr;
                if (row < N_NODES) {
                    #pragma unroll
                    for (int nf = 0; nf < 8; ++nf)
                        outf[(size_t)row * D + nf * 16 + arow] = v[nf] - lse;
                }
            }
        }
    }
}

extern "C" void kernel_launch(void* const* d_in, const int* in_sizes, int n_in,
                              void* d_out, int out_size, void* d_ws, size_t ws_size,
                              hipStream_t stream) {
    (void)in_sizes; (void)n_in; (void)out_size; (void)ws_size;
    const float* x  = (const float*)d_in[0];
    const int*   ei = (const int*)d_in[1];
    const int*   src = ei;
    const int*   dst = ei + N_EDGES;
    const float* W1 = (const float*)d_in[2];
    const float* b1 = (const float*)d_in[3];
    const float* e1 = (const float*)d_in[4];
    const float* W2 = (const float*)d_in[5];
    const float* b2 = (const float*)d_in[6];
    const float* e2 = (const float*)d_in[7];
    const float* W3 = (const float*)d_in[8];
    const float* b3 = (const float*)d_in[9];
    const float* e3 = (const float*)d_in[10];
    float* out = (float*)d_out;

    char* ws = (char*)d_ws;
    int*    rs           = (int*)ws;                             // 36 B
    int*    bucket_start = (int*)(ws + 1024);                    // 6.3 KB
    int*    bhist1       = (int*)(ws + 8192);                    // 16 KB
    int*    cbase1       = (int*)(ws + 24576);                   // 16 KB
    int*    bhist2       = (int*)(ws + 40960);                   // 401 KB
    int*    cbase2       = (int*)(ws + 442368);                  // 401 KB
    int*    row_ptr      = (int*)(ws + 851968);                  // 400 KB
    int*    deg          = (int*)(ws + 1253376);                 // 400 KB
    int*    perm         = (int*)(ws + 1654784);                 // 400 KB
    int*    bdh          = (int*)(ws + 2055168);                 // 64 KB
    int*    cbdeg        = (int*)(ws + 2120704);                 // 64 KB
    int*    col          = (int*)(ws + 2193408);                 // 6.4 MB
    ushort* wt_hi        = (ushort*)(ws + 8650752);              // 96 KB (3 layers)
    ushort* wt_lo        = (ushort*)(ws + 8749056);              // 96 KB
    ushort* xb           = (ushort*)(ws + 9437184);              // 25.6 MB (2 planes)
    ushort* hb           = (ushort*)(ws + 35651584);             // 25.6 MB (2 planes)
    u32*    epack1       = (u32*)(ws + 35651584);                // 6.4 MB (aliases hb; dead before layer 1)
    u32*    epack2       = (u32*)(ws + 42991616);                // 6.4 MB (aliases hb; dead before layer 1)

    // single cooperative build kernel (12 former dispatches)
    void* args[] = {
        (void*)&x, (void*)&xb, (void*)&src, (void*)&dst,
        (void*)&W1, (void*)&W2, (void*)&W3,
        (void*)&wt_hi, (void*)&wt_lo,
        (void*)&bhist1, (void*)&cbase1, (void*)&rs,
        (void*)&bhist2, (void*)&cbase2, (void*)&bucket_start,
        (void*)&epack1, (void*)&epack2,
        (void*)&row_ptr, (void*)&col, (void*)&deg,
        (void*)&bdh, (void*)&cbdeg, (void*)&perm
    };
    hipLaunchCooperativeKernel((void*)build_kernel, dim3(NB_COOP), dim3(256),
                               args, 0, stream);

    const int aggGrid = 2 * ((N_NODES + 31) / 32);    // 6250: plane = blockIdx&1
    const int gemmGrid = (N_NODES + 127) / 128;       // 782

    // layer 1
    aggregate_kernel<<<aggGrid, 256, 0, stream>>>(xb, row_ptr, col, perm, e1, hb);
    gemm_relu_mfma<0><<<gemmGrid, 256, 0, stream>>>(hb, wt_hi, wt_lo, b1, nullptr, xb);
    // layer 2
    aggregate_kernel<<<aggGrid, 256, 0, stream>>>(xb, row_ptr, col, perm, e2, hb);
    gemm_relu_mfma<0><<<gemmGrid, 256, 0, stream>>>(hb, wt_hi + D * D, wt_lo + D * D, b2, nullptr, xb);
    // layer 3 (+ fused log_softmax)
    aggregate_kernel<<<aggGrid, 256, 0, stream>>>(xb, row_ptr, col, perm, e3, hb);
    gemm_relu_mfma<1><<<gemmGrid, 256, 0, stream>>>(hb, wt_hi + 2 * D * D, wt_lo + 2 * D * D, b3, out, nullptr);
}

// Round 12
// 370.623 us; speedup vs baseline: 2.3948x; 2.3948x over previous
//
#include <hip/hip_runtime.h>
#include <hip/hip_bf16.h>

#define N_NODES 100000
#define N_EDGES 1600000
#define D 128
#define NRANGE 8
#define RANGE_SZ 12500          // nodes per level-1 range
#define SB_PER_RANGE 196        // 64-node buckets per range
#define NBUCKET (NRANGE * SB_PER_RANGE)  // 1568
#define G_PART 512
#define CH_PART 3125            // 512*3125 = 1,600,000 exact
#define G_DEG 128
#define CH_DEG 784              // 128*784 >= N_NODES
#define G_X2B 12500             // x2b blocks
#define PLANE ((size_t)N_NODES * 64)   // ushorts per feature-plane

typedef __attribute__((ext_vector_type(8))) short bf16x8;
typedef __attribute__((ext_vector_type(8))) unsigned short u16x8;
typedef __attribute__((ext_vector_type(4))) float f32x4;
typedef unsigned int u32;

__device__ inline ushort f2b(float x) {
    union { float f; unsigned u; } v; v.f = x;
    unsigned r = (v.u + 0x7fff + ((v.u >> 16) & 1)) >> 16;
    return (ushort)r;
}
__device__ inline float b2f(ushort b) {
    union { unsigned u; float f; } v; v.u = ((unsigned)b) << 16;
    return v.f;
}

// ---------------- prep: x2b(plane layout) ∥ hist1 ∥ wsplit3 ----------------
__global__ void prep_kernel(const float* __restrict__ x, ushort* __restrict__ xb,
                            const int* __restrict__ dst, int* __restrict__ bhist1,
                            const float* __restrict__ W1, const float* __restrict__ W2,
                            const float* __restrict__ W3,
                            ushort* __restrict__ wt_hi, ushort* __restrict__ wt_lo) {
    __shared__ int lh[NRANGE];
    int b = blockIdx.x;
    if (b < G_X2B) {
        int i = b * 256 + threadIdx.x;
        if (i < N_NODES * D / 4) {
            float4 v = ((const float4*)x)[i];
            ushort4 o;
            o.x = f2b(v.x); o.y = f2b(v.y); o.z = f2b(v.z); o.w = f2b(v.w);
            int node = i >> 5;            // 32 float4 per 128-feature row
            int f0 = (i & 31) * 4;        // feature offset 0..124
            int plane = f0 >> 6;
            *(ushort4*)(xb + plane * PLANE + (size_t)node * 64 + (f0 & 63)) = o;
        }
    } else if (b < G_X2B + G_PART) {
        int blk = b - G_X2B;
        if (threadIdx.x < NRANGE) lh[threadIdx.x] = 0;
        __syncthreads();
        int s0 = blk * CH_PART, s1 = s0 + CH_PART;
        if (s1 > N_EDGES) s1 = N_EDGES;
        for (int i = s0 + threadIdx.x; i < s1; i += 256)
            atomicAdd(&lh[dst[i] / RANGE_SZ], 1);
        __syncthreads();
        if (threadIdx.x < NRANGE) bhist1[blk * NRANGE + threadIdx.x] = lh[threadIdx.x];
    } else {
        int blk = b - G_X2B - G_PART;
        int layer = blk >> 6;
        int t = (blk & 63) * 256 + threadIdx.x;
        const float* W = layer == 0 ? W1 : layer == 1 ? W2 : W3;
        int k = t >> 7, n = t & 127;
        float w = W[t];
        ushort hi = f2b(w);
        ushort lo = f2b(w - b2f(hi));
        wt_hi[layer * D * D + n * D + k] = hi;
        wt_lo[layer * D * D + n * D + k] = lo;
    }
}

// ---------------- CSR build: atomic-free two-level counting sort ----------------

__global__ void scan1_kernel(const int* __restrict__ bhist1, int* __restrict__ cbase1,
                             int* __restrict__ rs) {
    int r = threadIdx.x >> 6, lane = threadIdx.x & 63;
    __shared__ int rtot[NRANGE], roff[NRANGE];
    int excl[8];
    int run = 0;
    #pragma unroll
    for (int seg = 0; seg < 8; ++seg) {
        int b = seg * 64 + lane;
        int v = bhist1[b * NRANGE + r];
        int sc = v;
        #pragma unroll
        for (int off = 1; off < 64; off <<= 1) {
            int y = __shfl_up(sc, off);
            if (lane >= off) sc += y;
        }
        excl[seg] = run + sc - v;
        run += __shfl(sc, 63);
    }
    if (lane == 63) rtot[r] = run;
    __syncthreads();
    if (threadIdx.x == 0) {
        int a = 0;
        for (int i = 0; i < NRANGE; ++i) { roff[i] = a; a += rtot[i]; }
    }
    __syncthreads();
    int base = roff[r];
    #pragma unroll
    for (int seg = 0; seg < 8; ++seg)
        cbase1[(seg * 64 + lane) * NRANGE + r] = base + excl[seg];
    if (threadIdx.x < NRANGE) rs[threadIdx.x] = roff[threadIdx.x];
    if (threadIdx.x == 0) rs[NRANGE] = N_EDGES;
}

__global__ void place1_kernel(const int* __restrict__ src, const int* __restrict__ dst,
                              const int* __restrict__ cbase1, u32* __restrict__ epack1) {
    __shared__ int cur[NRANGE];
    if (threadIdx.x < NRANGE) cur[threadIdx.x] = cbase1[blockIdx.x * NRANGE + threadIdx.x];
    __syncthreads();
    int s0 = blockIdx.x * CH_PART, s1 = s0 + CH_PART;
    if (s1 > N_EDGES) s1 = N_EDGES;
    for (int i = s0 + threadIdx.x; i < s1; i += 256) {
        int d = dst[i], s = src[i];
        int r = d / RANGE_SZ;
        int dl = d - r * RANGE_SZ;
        int p = atomicAdd(&cur[r], 1);
        epack1[p] = ((u32)dl << 17) | (u32)s;
    }
}

__global__ void hist2_kernel(const u32* __restrict__ epack1, const int* __restrict__ rs,
                             int* __restrict__ bhist2) {
    __shared__ int lh[SB_PER_RANGE];
    for (int i = threadIdx.x; i < SB_PER_RANGE; i += 256) lh[i] = 0;
    __syncthreads();
    int r = blockIdx.x >> 6, j = blockIdx.x & 63;
    int e0 = rs[r], e1 = rs[r + 1];
    int cs = (e1 - e0 + 63) >> 6;
    int s0 = e0 + j * cs, s1 = s0 + cs;
    if (s1 > e1) s1 = e1;
    for (int i = s0 + threadIdx.x; i < s1; i += 256)
        atomicAdd(&lh[epack1[i] >> 23], 1);
    __syncthreads();
    for (int i = threadIdx.x; i < SB_PER_RANGE; i += 256)
        bhist2[blockIdx.x * SB_PER_RANGE + i] = lh[i];
}

__global__ void scan2_kernel(const int* __restrict__ bhist2, const int* __restrict__ rs,
                             int* __restrict__ cbase2, int* __restrict__ bucket_start) {
    int r = blockIdx.x;
    __shared__ int tot[SB_PER_RANGE];
    __shared__ int base[SB_PER_RANGE];
    int sb = threadIdx.x;
    if (sb < SB_PER_RANGE) {
        int s = 0;
        for (int j = 0; j < 64; ++j) s += bhist2[(r * 64 + j) * SB_PER_RANGE + sb];
        tot[sb] = s;
    }
    __syncthreads();
    if (threadIdx.x == 0) {
        int a = 0;
        for (int i = 0; i < SB_PER_RANGE; ++i) { base[i] = a; a += tot[i]; }
    }
    __syncthreads();
    if (sb < SB_PER_RANGE) {
        int run = rs[r] + base[sb];
        bucket_start[r * SB_PER_RANGE + sb] = run;
        for (int j = 0; j < 64; ++j) {
            cbase2[(r * 64 + j) * SB_PER_RANGE + sb] = run;
            run += bhist2[(r * 64 + j) * SB_PER_RANGE + sb];
        }
    }
    if (r == NRANGE - 1 && threadIdx.x == 0) bucket_start[NBUCKET] = N_EDGES;
}

__global__ void place2_kernel(const u32* __restrict__ epack1, const int* __restrict__ rs,
                              const int* __restrict__ cbase2, u32* __restrict__ epack2) {
    __shared__ int cur[SB_PER_RANGE];
    for (int i = threadIdx.x; i < SB_PER_RANGE; i += 256)
        cur[i] = cbase2[blockIdx.x * SB_PER_RANGE + i];
    __syncthreads();
    int r = blockIdx.x >> 6, j = blockIdx.x & 63;
    int e0 = rs[r], e1 = rs[r + 1];
    int cs = (e1 - e0 + 63) >> 6;
    int s0 = e0 + j * cs, s1 = s0 + cs;
    if (s1 > e1) s1 = e1;
    for (int i = s0 + threadIdx.x; i < s1; i += 256) {
        u32 e = epack1[i];
        int sb = e >> 23;
        int p = atomicAdd(&cur[sb], 1);
        epack2[p] = e & 0x7FFFFFu;
    }
}

// per-bucket LDS counting sort -> col + row_ptr + deg  (1568 blocks)
__global__ void sort3_kernel(const u32* __restrict__ epack2, const int* __restrict__ bucket_start,
                             int* __restrict__ row_ptr, int* __restrict__ col,
                             int* __restrict__ deg) {
    int b = blockIdx.x;
    int r = b / SB_PER_RANGE, sb = b - r * SB_PER_RANGE;
    int node_base = r * RANGE_SZ + sb * 64;
    int nb = r * RANGE_SZ + RANGE_SZ - node_base;
    if (nb > 64) nb = 64;
    int e0 = bucket_start[b], e1 = bucket_start[b + 1];
    __shared__ int hist[64], cur[64];
    if (threadIdx.x < 64) hist[threadIdx.x] = 0;
    __syncthreads();
    for (int i = e0 + threadIdx.x; i < e1; i += 256)
        atomicAdd(&hist[(epack2[i] >> 17) & 63], 1);
    __syncthreads();
    if (threadIdx.x < 64) {   // wave 0
        int v = hist[threadIdx.x];
        int sc = v;
        #pragma unroll
        for (int off = 1; off < 64; off <<= 1) {
            int y = __shfl_up(sc, off);
            if (threadIdx.x >= off) sc += y;
        }
        int ex = e0 + sc - v;
        cur[threadIdx.x] = ex;
        if (threadIdx.x < nb) {
            row_ptr[node_base + threadIdx.x] = ex;
            deg[node_base + threadIdx.x] = v;
        }
    }
    __syncthreads();
    for (int i = e0 + threadIdx.x; i < e1; i += 256) {
        u32 e = epack2[i];
        int l = (e >> 17) & 63;
        int p = atomicAdd(&cur[l], 1);
        col[p] = (int)(e & 0x1FFFFu);
    }
    if (b == NBUCKET - 1 && threadIdx.x == 0) row_ptr[N_NODES] = N_EDGES;
}

// ---------------- degree-binned node permutation (atomic-free) ----------------

__global__ void deghist_kernel(const int* __restrict__ deg, int* __restrict__ bdh) {
    __shared__ int lh[128];
    if (threadIdx.x < 128) lh[threadIdx.x] = 0;
    __syncthreads();
    int s0 = blockIdx.x * CH_DEG, s1 = s0 + CH_DEG;
    if (s1 > N_NODES) s1 = N_NODES;
    for (int i = s0 + threadIdx.x; i < s1; i += 256)
        atomicAdd(&lh[min(deg[i], 127)], 1);
    __syncthreads();
    if (threadIdx.x < 128) bdh[blockIdx.x * 128 + threadIdx.x] = lh[threadIdx.x];
}

__global__ void degscan_kernel(const int* __restrict__ bdh, int* __restrict__ cbdeg) {
    __shared__ int sh[128];
    int t = threadIdx.x;
    int tot = 0;
    for (int j = 0; j < G_DEG; ++j) tot += bdh[j * 128 + t];
    sh[t] = tot;
    __syncthreads();
    if (t == 0) {
        int run = 0;
        for (int b = 127; b >= 0; --b) { int c = sh[b]; sh[b] = run; run += c; }
    }
    __syncthreads();
    int run = sh[t];
    for (int j = 0; j < G_DEG; ++j) {
        cbdeg[j * 128 + t] = run;
        run += bdh[j * 128 + t];
    }
}

__global__ void degplace_kernel(const int* __restrict__ deg, const int* __restrict__ cbdeg,
                                int* __restrict__ perm) {
    __shared__ int cur[128];
    if (threadIdx.x < 128) cur[threadIdx.x] = cbdeg[blockIdx.x * 128 + threadIdx.x];
    __syncthreads();
    int s0 = blockIdx.x * CH_DEG, s1 = s0 + CH_DEG;
    if (s1 > N_NODES) s1 = N_NODES;
    for (int i = s0 + threadIdx.x; i < s1; i += 256) {
        int p = atomicAdd(&cur[min(deg[i], 127)], 1);
        perm[p] = i;
    }
}

// ---------------- GIN layer ----------------

// plane-split aggregate: plane = blockIdx&1; 8-lane group per (node, plane).
__global__ void aggregate_kernel(const ushort* __restrict__ xb, const int* __restrict__ row_ptr,
                                 const int* __restrict__ col, const int* __restrict__ perm,
                                 const float* __restrict__ eps_p, ushort* __restrict__ hb) {
    int plane = blockIdx.x & 1;
    int task = threadIdx.x >> 3;
    int l8 = threadIdx.x & 7;
    int qidx = (blockIdx.x >> 1) * 32 + task;
    if (qidx >= N_NODES) return;
    int node = perm[qidx];
    const ushort* xp = xb + plane * PLANE;
    int beg = row_ptr[node], end = row_ptr[node + 1];
    float a0[8] = {0,0,0,0,0,0,0,0};
    float a1[8] = {0,0,0,0,0,0,0,0};
    int e = beg;
    for (; e + 7 < end; e += 8) {
        int s[8];
        #pragma unroll
        for (int j = 0; j < 8; ++j) s[j] = col[e + j];
        u16x8 v[8];
        #pragma unroll
        for (int j = 0; j < 8; ++j)
            v[j] = *(const u16x8*)(xp + ((size_t)s[j] << 6) + l8 * 8);
        #pragma unroll
        for (int j = 0; j < 8; ++j) {
            float* a = (j & 1) ? a1 : a0;
            #pragma unroll
            for (int k = 0; k < 8; ++k) a[k] += b2f(v[j][k]);
        }
    }
    if (e + 3 < end) {
        int s[4];
        #pragma unroll
        for (int j = 0; j < 4; ++j) s[j] = col[e + j];
        u16x8 v[4];
        #pragma unroll
        for (int j = 0; j < 4; ++j)
            v[j] = *(const u16x8*)(xp + ((size_t)s[j] << 6) + l8 * 8);
        #pragma unroll
        for (int j = 0; j < 4; ++j) {
            float* a = (j & 1) ? a1 : a0;
            #pragma unroll
            for (int k = 0; k < 8; ++k) a[k] += b2f(v[j][k]);
        }
        e += 4;
    }
    for (; e < end; ++e) {
        int s = col[e];
        u16x8 v = *(const u16x8*)(xp + ((size_t)s << 6) + l8 * 8);
        #pragma unroll
        for (int k = 0; k < 8; ++k) a0[k] += b2f(v[k]);
    }
    float scale = 1.0f + *eps_p;
    u16x8 xi = *(const u16x8*)(xp + ((size_t)node << 6) + l8 * 8);
    u16x8 ho;
    #pragma unroll
    for (int k = 0; k < 8; ++k) {
        float o = a0[k] + a1[k] + scale * b2f(xi[k]);
        ho[k] = f2b(o);
    }
    *(u16x8*)(hb + plane * PLANE + ((size_t)node << 6) + l8 * 8) = ho;
}

// out = relu(h @ W + b); A = bf16 h (plane layout), W = hi/lo split.
// MODE 0: write bf16 (plane layout); MODE 1: fused log_softmax, write f32 row-major.
template <int MODE>
__launch_bounds__(256, 2)
__global__ void gemm_relu_mfma(const ushort* __restrict__ hb,
                               const ushort* __restrict__ wt_hi, const ushort* __restrict__ wt_lo,
                               const float* __restrict__ bias,
                               float* __restrict__ outf, ushort* __restrict__ outb) {
    int wv = threadIdx.x >> 6, lane = threadIdx.x & 63;
    int r0 = blockIdx.x * 128 + wv * 32;
    int arow = lane & 15, agrp = lane >> 4;
    bf16x8 Ah[2][4];
    #pragma unroll
    for (int mf = 0; mf < 2; ++mf) {
        int row = r0 + mf * 16 + arow;
        size_t rb0 = (size_t)row << 6;
        #pragma unroll
        for (int kf = 0; kf < 4; ++kf) {
            size_t off = (kf < 2) ? rb0 + kf * 32 + agrp * 8
                                  : PLANE + rb0 + (kf - 2) * 32 + agrp * 8;
            Ah[mf][kf] = *(const bf16x8*)(hb + off);
        }
    }
    f32x4 acc[2][8];
    #pragma unroll
    for (int mf = 0; mf < 2; ++mf)
        #pragma unroll
        for (int nf = 0; nf < 8; ++nf)
            acc[mf][nf] = (f32x4){0.f, 0.f, 0.f, 0.f};
    #pragma unroll
    for (int nf = 0; nf < 8; ++nf) {
        #pragma unroll
        for (int kf = 0; kf < 4; ++kf) {
            size_t wb = (size_t)(nf * 16 + arow) * D + kf * 32 + agrp * 8;
            bf16x8 bh = *(const bf16x8*)(wt_hi + wb);
            bf16x8 bl = *(const bf16x8*)(wt_lo + wb);
            #pragma unroll
            for (int mf = 0; mf < 2; ++mf) {
                acc[mf][nf] = __builtin_amdgcn_mfma_f32_16x16x32_bf16(Ah[mf][kf], bh, acc[mf][nf], 0, 0, 0);
                acc[mf][nf] = __builtin_amdgcn_mfma_f32_16x16x32_bf16(Ah[mf][kf], bl, acc[mf][nf], 0, 0, 0);
            }
        }
    }
    float bcol[8];
    #pragma unroll
    for (int nf = 0; nf < 8; ++nf) bcol[nf] = bias[nf * 16 + arow];
    if (MODE == 0) {
        int crow = agrp * 4;
        #pragma unroll
        for (int mf = 0; mf < 2; ++mf) {
            #pragma unroll
            for (int nf = 0; nf < 8; ++nf) {
                int coln = nf * 16 + arow;
                size_t pbase = (nf >> 2) ? PLANE : 0;
                #pragma unroll
                for (int r = 0; r < 4; ++r) {
                    int row = r0 + mf * 16 + crow + r;
                    if (row < N_NODES)
                        outb[pbase + ((size_t)row << 6) + (coln & 63)] =
                            f2b(fmaxf(acc[mf][nf][r] + bcol[nf], 0.f));
                }
            }
        }
    } else {
        #pragma unroll
        for (int mf = 0; mf < 2; ++mf) {
            #pragma unroll
            for (int rr = 0; rr < 4; ++rr) {
                float v[8];
                #pragma unroll
                for (int nf = 0; nf < 8; ++nf)
                    v[nf] = fmaxf(acc[mf][nf][rr] + bcol[nf], 0.f);
                float m = v[0];
                #pragma unroll
                for (int nf = 1; nf < 8; ++nf) m = fmaxf(m, v[nf]);
                #pragma unroll
                for (int off = 1; off < 16; off <<= 1) m = fmaxf(m, __shfl_xor(m, off));
                float s = 0.f;
                #pragma unroll
                for (int nf = 0; nf < 8; ++nf) s += __expf(v[nf] - m);
                #pragma unroll
                for (int off = 1; off < 16; off <<= 1) s += __shfl_xor(s, off);
                float lse = m + __logf(s);
                int row = r0 + mf * 16 + agrp * 4 + rr;
                if (row < N_NODES) {
                    #pragma unroll
                    for (int nf = 0; nf < 8; ++nf)
                        outf[(size_t)row * D + nf * 16 + arow] = v[nf] - lse;
                }
            }
        }
    }
}

extern "C" void kernel_launch(void* const* d_in, const int* in_sizes, int n_in,
                              void* d_out, int out_size, void* d_ws, size_t ws_size,
                              hipStream_t stream) {
    (void)in_sizes; (void)n_in; (void)out_size; (void)ws_size;
    const float* x  = (const float*)d_in[0];
    const int*   ei = (const int*)d_in[1];
    const int*   src = ei;
    const int*   dst = ei + N_EDGES;
    const float* W1 = (const float*)d_in[2];
    const float* b1 = (const float*)d_in[3];
    const float* e1 = (const float*)d_in[4];
    const float* W2 = (const float*)d_in[5];
    const float* b2 = (const float*)d_in[6];
    const float* e2 = (const float*)d_in[7];
    const float* W3 = (const float*)d_in[8];
    const float* b3 = (const float*)d_in[9];
    const float* e3 = (const float*)d_in[10];
    float* out = (float*)d_out;

    char* ws = (char*)d_ws;
    int*    rs           = (int*)ws;                             // 36 B
    int*    bucket_start = (int*)(ws + 1024);                    // 6.3 KB
    int*    bhist1       = (int*)(ws + 8192);                    // 16 KB
    int*    cbase1       = (int*)(ws + 24576);                   // 16 KB
    int*    bhist2       = (int*)(ws + 40960);                   // 401 KB
    int*    cbase2       = (int*)(ws + 442368);                  // 401 KB
    int*    row_ptr      = (int*)(ws + 851968);                  // 400 KB
    int*    deg          = (int*)(ws + 1253376);                 // 400 KB
    int*    perm         = (int*)(ws + 1654784);                 // 400 KB
    int*    bdh          = (int*)(ws + 2055168);                 // 64 KB
    int*    cbdeg        = (int*)(ws + 2120704);                 // 64 KB
    int*    col          = (int*)(ws + 2193408);                 // 6.4 MB
    ushort* wt_hi        = (ushort*)(ws + 8650752);              // 96 KB (3 layers)
    ushort* wt_lo        = (ushort*)(ws + 8749056);              // 96 KB
    ushort* xb           = (ushort*)(ws + 9437184);              // 25.6 MB (2 planes)
    ushort* hb           = (ushort*)(ws + 35651584);             // 25.6 MB (2 planes)
    u32*    epack1       = (u32*)(ws + 35651584);                // 6.4 MB (aliases hb; dead before layer 1)
    u32*    epack2       = (u32*)(ws + 42991616);                // 6.4 MB (aliases hb; dead before layer 1)

    // prep: x2b (12500) ∥ hist1 (512) ∥ wsplit3 (192)
    prep_kernel<<<G_X2B + G_PART + 192, 256, 0, stream>>>(x, xb, dst, bhist1,
                                                          W1, W2, W3, wt_hi, wt_lo);

    scan1_kernel<<<1, 512, 0, stream>>>(bhist1, cbase1, rs);
    place1_kernel<<<G_PART, 256, 0, stream>>>(src, dst, cbase1, epack1);
    hist2_kernel<<<G_PART, 256, 0, stream>>>(epack1, rs, bhist2);
    scan2_kernel<<<NRANGE, 256, 0, stream>>>(bhist2, rs, cbase2, bucket_start);
    place2_kernel<<<G_PART, 256, 0, stream>>>(epack1, rs, cbase2, epack2);
    sort3_kernel<<<NBUCKET, 256, 0, stream>>>(epack2, bucket_start, row_ptr, col, deg);

    deghist_kernel<<<G_DEG, 256, 0, stream>>>(deg, bdh);
    degscan_kernel<<<1, 128, 0, stream>>>(bdh, cbdeg);
    degplace_kernel<<<G_DEG, 256, 0, stream>>>(deg, cbdeg, perm);

    const int aggGrid = 2 * ((N_NODES + 31) / 32);    // 6250: plane = blockIdx&1
    const int gemmGrid = (N_NODES + 127) / 128;       // 782

    // layer 1
    aggregate_kernel<<<aggGrid, 256, 0, stream>>>(xb, row_ptr, col, perm, e1, hb);
    gemm_relu_mfma<0><<<gemmGrid, 256, 0, stream>>>(hb, wt_hi, wt_lo, b1, nullptr, xb);
    // layer 2
    aggregate_kernel<<<aggGrid, 256, 0, stream>>>(xb, row_ptr, col, perm, e2, hb);
    gemm_relu_mfma<0><<<gemmGrid, 256, 0, stream>>>(hb, wt_hi + D * D, wt_lo + D * D, b2, nullptr, xb);
    // layer 3 (+ fused log_softmax)
    aggregate_kernel<<<aggGrid, 256, 0, stream>>>(xb, row_ptr, col, perm, e3, hb);
    gemm_relu_mfma<1><<<gemmGrid, 256, 0, stream>>>(hb, wt_hi + 2 * D * D, wt_lo + 2 * D * D, b3, out, nullptr);
}